// Round 1
// baseline (622.932 us; speedup 1.0000x reference)
//
#include <hip/hip_runtime.h>

#define NN 100000      // nodes
#define NE 1600000     // edges
#define DD 128         // input dim
#define MD 512         // mlp dim = 128*4
#define SEL 16384      // senders count
#define MROWS 32768    // senders + receivers rows

typedef __attribute__((ext_vector_type(8))) short bf16x8;
typedef __attribute__((ext_vector_type(4))) float f32x4;

__device__ __forceinline__ unsigned short f2bf(float f) {
  unsigned u = __float_as_uint(f);
  u += 0x7fff + ((u >> 16) & 1);   // round-to-nearest-even
  return (unsigned short)(u >> 16);
}

// ---- degree histogram over dst ----
__global__ void k_deg(const int* __restrict__ dst, int* __restrict__ deg) {
  int e = blockIdx.x * blockDim.x + threadIdx.x;
  if (e < NE) atomicAdd(&deg[dst[e]], 1);
}

__global__ void k_dinv(const int* __restrict__ deg, float* __restrict__ dinv) {
  int n = blockIdx.x * blockDim.x + threadIdx.x;
  if (n < NN) dinv[n] = rsqrtf(fmaxf((float)deg[n], 1.0f));
}

// ---- exclusive scan of deg -> rowstart (3-kernel) ----
__global__ __launch_bounds__(1024) void k_scan1(const int* __restrict__ deg,
                                                int* __restrict__ excl,
                                                int* __restrict__ part) {
  __shared__ int sm[1024];
  int tid = threadIdx.x;
  int i = blockIdx.x * 1024 + tid;
  int v = (i < NN) ? deg[i] : 0;
  sm[tid] = v;
  __syncthreads();
  for (int o = 1; o < 1024; o <<= 1) {
    int t = (tid >= o) ? sm[tid - o] : 0;
    __syncthreads();
    sm[tid] += t;
    __syncthreads();
  }
  if (i < NN) excl[i] = sm[tid] - v;
  if (tid == 1023) part[blockIdx.x] = sm[1023];
}

__global__ __launch_bounds__(256) void k_scan2(int* __restrict__ part, int nb) {
  __shared__ int sm[256];
  int tid = threadIdx.x;
  int v = (tid < nb) ? part[tid] : 0;
  sm[tid] = v;
  __syncthreads();
  for (int o = 1; o < 256; o <<= 1) {
    int t = (tid >= o) ? sm[tid - o] : 0;
    __syncthreads();
    sm[tid] += t;
    __syncthreads();
  }
  if (tid < nb) part[tid] = sm[tid] - v;
}

__global__ void k_scan3(int* __restrict__ excl, const int* __restrict__ part) {
  int i = blockIdx.x * blockDim.x + threadIdx.x;
  if (i < NN) excl[i] += part[i >> 10];
}

// ---- CSR fill: csr[slot] = {src, norm_weight} ----
__global__ void k_fill(const int* __restrict__ src, const int* __restrict__ dst,
                       const float* __restrict__ dinv, const int* __restrict__ rowstart,
                       int* __restrict__ cursor, int2* __restrict__ csr) {
  int e = blockIdx.x * blockDim.x + threadIdx.x;
  if (e >= NE) return;
  int s = src[e], d = dst[e];
  float w = dinv[s] * dinv[d];
  int pos = atomicAdd(&cursor[d], 1);
  csr[rowstart[d] + pos] = make_int2(s, __float_as_int(w));
}

// ---- per-layer aggregation: one wave per dst node, no output atomics ----
__global__ __launch_bounds__(256) void k_agg(const int* __restrict__ rowstart,
                                             const int* __restrict__ deg,
                                             const int2* __restrict__ csr,
                                             const float* __restrict__ xin,
                                             float* __restrict__ xout) {
  const int lane = threadIdx.x & 63;
  const int wid = (blockIdx.x * blockDim.x + threadIdx.x) >> 6;
  const int nw = (gridDim.x * blockDim.x) >> 6;
  for (int n = wid; n < NN; n += nw) {
    const int start = rowstart[n];
    const int cnt = deg[n];
    float2 a0 = make_float2(0.f, 0.f), a1 = make_float2(0.f, 0.f);
    int j = 0;
    for (; j + 2 <= cnt; j += 2) {
      const int2 e0 = csr[start + j];
      const int2 e1 = csr[start + j + 1];
      const float w0 = __int_as_float(e0.y);
      const float w1 = __int_as_float(e1.y);
      const float2 v0 = ((const float2*)(xin + (size_t)e0.x * DD))[lane];
      const float2 v1 = ((const float2*)(xin + (size_t)e1.x * DD))[lane];
      a0.x = fmaf(w0, v0.x, a0.x); a0.y = fmaf(w0, v0.y, a0.y);
      a1.x = fmaf(w1, v1.x, a1.x); a1.y = fmaf(w1, v1.y, a1.y);
    }
    if (j < cnt) {
      const int2 e0 = csr[start + j];
      const float w0 = __int_as_float(e0.y);
      const float2 v0 = ((const float2*)(xin + (size_t)e0.x * DD))[lane];
      a0.x = fmaf(w0, v0.x, a0.x); a0.y = fmaf(w0, v0.y, a0.y);
    }
    float2 r; r.x = a0.x + a1.x; r.y = a0.y + a1.y;
    ((float2*)(xout + (size_t)n * DD))[lane] = r;
  }
}

// ---- gather + l2-normalize selected rows -> bf16 A-matrix slice ----
__global__ __launch_bounds__(256) void k_gnorm(const int* __restrict__ sl,
                                               const int* __restrict__ rl,
                                               const float* __restrict__ xin,
                                               unsigned short* __restrict__ Abf,
                                               int colbase) {
  const int lane = threadIdx.x & 63;
  const int row = blockIdx.x * 4 + (threadIdx.x >> 6);
  if (row >= MROWS) return;
  const int node = (row < SEL) ? sl[row] : rl[row - SEL];
  const float2 v = ((const float2*)(xin + (size_t)node * DD))[lane];
  float ss = fmaf(v.x, v.x, v.y * v.y);
  #pragma unroll
  for (int m = 32; m >= 1; m >>= 1) ss += __shfl_xor(ss, m);
  const float sc = 1.0f / fmaxf(sqrtf(ss), 1e-12f);
  unsigned short b0 = f2bf(v.x * sc), b1 = f2bf(v.y * sc);
  unsigned pack = ((unsigned)b1 << 16) | (unsigned)b0;
  *(unsigned*)(Abf + (size_t)row * MD + colbase + lane * 2) = pack;
}

// ---- W f32 -> bf16 ----
__global__ void k_wconv(const float* __restrict__ W, unsigned short* __restrict__ Wb) {
  int i = blockIdx.x * blockDim.x + threadIdx.x;
  if (i >= (MD * MD) / 4) return;
  float4 v = ((const float4*)W)[i];
  ushort4 o;
  o.x = f2bf(v.x); o.y = f2bf(v.y); o.z = f2bf(v.z); o.w = f2bf(v.w);
  ((ushort4*)Wb)[i] = o;
}

// ---- MFMA GEMM: out[i][j] = sum_k A[i][k]*W[j][k] + bias[j] ----
// A: [32768][512] bf16, B=W: [512][512] bf16 (row j, contiguous k), out f32
__global__ __launch_bounds__(256) void k_gemm(const unsigned short* __restrict__ A,
                                              const unsigned short* __restrict__ B,
                                              const float* __restrict__ bias,
                                              float* __restrict__ out) {
  __shared__ unsigned short As[128][40];  // +8 pad breaks bank conflicts
  __shared__ unsigned short Bs[128][40];
  const int t = threadIdx.x;
  const int mt = blockIdx.x >> 2, nt = blockIdx.x & 3;
  const int i0 = mt * 128, j0 = nt * 128;
  const int lane = t & 63, wid = t >> 6;
  const int wr = wid >> 1, wc = wid & 1;    // 2x2 waves, 64x64 each
  const int fr = lane & 15, kg = lane >> 4; // fragment row/col, k-group
  f32x4 acc[4][4] = {};
  for (int k0 = 0; k0 < MD; k0 += 32) {
    #pragma unroll
    for (int rep = 0; rep < 2; ++rep) {
      int id = t + rep * 256;
      int row = id >> 2, seg = id & 3;  // 128 rows x 4 segs of 8 bf16
      float4 va = *(const float4*)(A + (size_t)(i0 + row) * MD + k0 + seg * 8);
      *(float4*)(&As[row][seg * 8]) = va;
      float4 vb = *(const float4*)(B + (size_t)(j0 + row) * MD + k0 + seg * 8);
      *(float4*)(&Bs[row][seg * 8]) = vb;
    }
    __syncthreads();
    bf16x8 af[4], bfr[4];
    #pragma unroll
    for (int m = 0; m < 4; ++m)
      af[m] = *(const bf16x8*)(&As[wr * 64 + m * 16 + fr][kg * 8]);
    #pragma unroll
    for (int n = 0; n < 4; ++n)
      bfr[n] = *(const bf16x8*)(&Bs[wc * 64 + n * 16 + fr][kg * 8]);
    #pragma unroll
    for (int m = 0; m < 4; ++m)
      #pragma unroll
      for (int n = 0; n < 4; ++n)
        acc[m][n] = __builtin_amdgcn_mfma_f32_16x16x32_bf16(af[m], bfr[n], acc[m][n], 0, 0, 0);
    __syncthreads();
  }
  #pragma unroll
  for (int n = 0; n < 4; ++n) {
    int col = j0 + wc * 64 + n * 16 + fr;
    float bv = bias[col];
    #pragma unroll
    for (int m = 0; m < 4; ++m) {
      int r0 = i0 + wr * 64 + m * 16 + kg * 4;
      #pragma unroll
      for (int r = 0; r < 4; ++r)
        out[(size_t)(r0 + r) * MD + col] = acc[m][n][r] + bv;
    }
  }
}

extern "C" void kernel_launch(void* const* d_in, const int* in_sizes, int n_in,
                              void* d_out, int out_size, void* d_ws, size_t ws_size,
                              hipStream_t stream) {
  const float* emb = (const float*)d_in[0];
  const int* ei = (const int*)d_in[1];      // int32 per harness contract
  const int* esrc = ei;                     // edge_index[0]
  const int* edst = ei + NE;                // edge_index[1]
  const int* send = (const int*)d_in[2];
  const int* recv = (const int*)d_in[3];
  const float* W = (const float*)d_in[4];
  const float* bias = (const float*)d_in[5];
  float* out = (float*)d_out;

  char* ws = (char*)d_ws;
  size_t off = 0;
  auto take = [&](size_t b) {
    char* p = ws + off;
    off = (off + b + 1023) & ~(size_t)1023;
    return p;
  };
  int* degI = (int*)take((size_t)NN * 4);
  float* dinv = (float*)take((size_t)NN * 4);
  int* rowstart = (int*)take((size_t)NN * 4);
  int* cursor = (int*)take((size_t)NN * 4);
  int* part = (int*)take(256 * 4);
  int2* csr = (int2*)take((size_t)NE * 8);
  float* xA = (float*)take((size_t)NN * DD * 4);
  float* xB = (float*)take((size_t)NN * DD * 4);
  unsigned short* Abf = (unsigned short*)take((size_t)MROWS * MD * 2);
  unsigned short* Wbf = (unsigned short*)take((size_t)MD * MD * 2);
  (void)ws_size; (void)in_sizes; (void)n_in; (void)out_size;

  hipMemsetAsync(degI, 0, (size_t)NN * 4, stream);
  hipMemsetAsync(cursor, 0, (size_t)NN * 4, stream);

  k_deg<<<(NE + 255) / 256, 256, 0, stream>>>(edst, degI);
  k_dinv<<<(NN + 255) / 256, 256, 0, stream>>>(degI, dinv);
  const int NB = (NN + 1023) / 1024;
  k_scan1<<<NB, 1024, 0, stream>>>(degI, rowstart, part);
  k_scan2<<<1, 256, 0, stream>>>(part, NB);
  k_scan3<<<(NN + 255) / 256, 256, 0, stream>>>(rowstart, part);
  k_fill<<<(NE + 255) / 256, 256, 0, stream>>>(esrc, edst, dinv, rowstart, cursor, csr);
  k_wconv<<<(MD * MD / 4 + 255) / 256, 256, 0, stream>>>(W, Wbf);

  // layer 0 z-slice from emb, then 3 propagation layers with fused z-gather
  k_gnorm<<<MROWS / 4, 256, 0, stream>>>(send, recv, emb, Abf, 0);
  k_agg<<<2048, 256, 0, stream>>>(rowstart, degI, csr, emb, xA);
  k_gnorm<<<MROWS / 4, 256, 0, stream>>>(send, recv, xA, Abf, 128);
  k_agg<<<2048, 256, 0, stream>>>(rowstart, degI, csr, xA, xB);
  k_gnorm<<<MROWS / 4, 256, 0, stream>>>(send, recv, xB, Abf, 256);
  k_agg<<<2048, 256, 0, stream>>>(rowstart, degI, csr, xB, xA);
  k_gnorm<<<MROWS / 4, 256, 0, stream>>>(send, recv, xA, Abf, 384);

  k_gemm<<<(MROWS / 128) * (MD / 128), 256, 0, stream>>>(Abf, Wbf, bias, out);
}

// Round 2
// 442.247 us; speedup vs baseline: 1.4086x; 1.4086x over previous
//
#include <hip/hip_runtime.h>

#define NN 100000      // nodes
#define NE 1600000     // edges
#define DD 128         // input dim (elements per row)
#define MD 512         // mlp dim = 128*4
#define SEL 16384      // senders count
#define MROWS 32768    // senders + receivers rows

typedef __attribute__((ext_vector_type(8))) short bf16x8;
typedef __attribute__((ext_vector_type(4))) float f32x4;

__device__ __forceinline__ unsigned short f2bf(float f) {
  unsigned u = __float_as_uint(f);
  u += 0x7fff + ((u >> 16) & 1);   // round-to-nearest-even
  return (unsigned short)(u >> 16);
}
__device__ __forceinline__ float bflo(unsigned v) { return __uint_as_float(v << 16); }
__device__ __forceinline__ float bfhi(unsigned v) { return __uint_as_float(v & 0xffff0000u); }

// ---- degree histogram over dst ----
__global__ void k_deg(const int* __restrict__ dst, int* __restrict__ deg) {
  int e = blockIdx.x * blockDim.x + threadIdx.x;
  if (e < NE) atomicAdd(&deg[dst[e]], 1);
}

__global__ void k_dinv(const int* __restrict__ deg, float* __restrict__ dinv) {
  int n = blockIdx.x * blockDim.x + threadIdx.x;
  if (n < NN) dinv[n] = rsqrtf(fmaxf((float)deg[n], 1.0f));
}

// ---- exclusive scan of deg -> rowstart (3-kernel) ----
__global__ __launch_bounds__(1024) void k_scan1(const int* __restrict__ deg,
                                                int* __restrict__ excl,
                                                int* __restrict__ part) {
  __shared__ int sm[1024];
  int tid = threadIdx.x;
  int i = blockIdx.x * 1024 + tid;
  int v = (i < NN) ? deg[i] : 0;
  sm[tid] = v;
  __syncthreads();
  for (int o = 1; o < 1024; o <<= 1) {
    int t = (tid >= o) ? sm[tid - o] : 0;
    __syncthreads();
    sm[tid] += t;
    __syncthreads();
  }
  if (i < NN) excl[i] = sm[tid] - v;
  if (tid == 1023) part[blockIdx.x] = sm[1023];
}

__global__ __launch_bounds__(256) void k_scan2(int* __restrict__ part, int nb) {
  __shared__ int sm[256];
  int tid = threadIdx.x;
  int v = (tid < nb) ? part[tid] : 0;
  sm[tid] = v;
  __syncthreads();
  for (int o = 1; o < 256; o <<= 1) {
    int t = (tid >= o) ? sm[tid - o] : 0;
    __syncthreads();
    sm[tid] += t;
    __syncthreads();
  }
  if (tid < nb) part[tid] = sm[tid] - v;
}

__global__ void k_scan3(int* __restrict__ excl, const int* __restrict__ part) {
  int i = blockIdx.x * blockDim.x + threadIdx.x;
  if (i < NN) excl[i] += part[i >> 10];
}

// ---- CSR fill: csr[slot] = {src, norm_weight} ----
__global__ void k_fill(const int* __restrict__ src, const int* __restrict__ dst,
                       const float* __restrict__ dinv, const int* __restrict__ rowstart,
                       int* __restrict__ cursor, int2* __restrict__ csr) {
  int e = blockIdx.x * blockDim.x + threadIdx.x;
  if (e >= NE) return;
  int s = src[e], d = dst[e];
  float w = dinv[s] * dinv[d];
  int pos = atomicAdd(&cursor[d], 1);
  csr[rowstart[d] + pos] = make_int2(s, __float_as_int(w));
}

// ---- mark + compact the nodes needed by the final layer ----
__global__ void k_mark(const int* __restrict__ sl, const int* __restrict__ rl,
                       int* __restrict__ mark) {
  int i = blockIdx.x * blockDim.x + threadIdx.x;
  if (i < SEL) mark[sl[i]] = 1;
  else if (i < 2 * SEL) mark[rl[i - SEL]] = 1;
}

__global__ void k_compact(const int* __restrict__ mark, int* __restrict__ list,
                          int* __restrict__ cnt) {
  int n = blockIdx.x * blockDim.x + threadIdx.x;
  if (n < NN && mark[n]) {
    int p = atomicAdd(cnt, 1);
    list[p] = n;
  }
}

// ---- per-node bf16 aggregation body: wave per node, lane holds 2 elems ----
__device__ __forceinline__ void agg_row(int n, int lane,
                                        const int* __restrict__ rowstart,
                                        const int* __restrict__ deg,
                                        const int2* __restrict__ csr,
                                        const unsigned short* __restrict__ xin,
                                        unsigned short* __restrict__ xout) {
  const int start = rowstart[n];
  const int cnt = deg[n];
  float ax0 = 0.f, ay0 = 0.f, ax1 = 0.f, ay1 = 0.f;
  float ax2 = 0.f, ay2 = 0.f, ax3 = 0.f, ay3 = 0.f;
  int j = 0;
  for (; j + 4 <= cnt; j += 4) {
    const int2 e0 = csr[start + j], e1 = csr[start + j + 1];
    const int2 e2 = csr[start + j + 2], e3 = csr[start + j + 3];
    const unsigned v0 = ((const unsigned*)(xin + (size_t)e0.x * DD))[lane];
    const unsigned v1 = ((const unsigned*)(xin + (size_t)e1.x * DD))[lane];
    const unsigned v2 = ((const unsigned*)(xin + (size_t)e2.x * DD))[lane];
    const unsigned v3 = ((const unsigned*)(xin + (size_t)e3.x * DD))[lane];
    const float w0 = __int_as_float(e0.y), w1 = __int_as_float(e1.y);
    const float w2 = __int_as_float(e2.y), w3 = __int_as_float(e3.y);
    ax0 = fmaf(w0, bflo(v0), ax0); ay0 = fmaf(w0, bfhi(v0), ay0);
    ax1 = fmaf(w1, bflo(v1), ax1); ay1 = fmaf(w1, bfhi(v1), ay1);
    ax2 = fmaf(w2, bflo(v2), ax2); ay2 = fmaf(w2, bfhi(v2), ay2);
    ax3 = fmaf(w3, bflo(v3), ax3); ay3 = fmaf(w3, bfhi(v3), ay3);
  }
  for (; j < cnt; ++j) {
    const int2 e0 = csr[start + j];
    const unsigned v0 = ((const unsigned*)(xin + (size_t)e0.x * DD))[lane];
    const float w0 = __int_as_float(e0.y);
    ax0 = fmaf(w0, bflo(v0), ax0); ay0 = fmaf(w0, bfhi(v0), ay0);
  }
  const float rx = (ax0 + ax1) + (ax2 + ax3);
  const float ry = (ay0 + ay1) + (ay2 + ay3);
  const unsigned pack = ((unsigned)f2bf(ry) << 16) | (unsigned)f2bf(rx);
  ((unsigned*)(xout + (size_t)n * DD))[lane] = pack;
}

__global__ __launch_bounds__(256) void k_agg(const int* __restrict__ rowstart,
                                             const int* __restrict__ deg,
                                             const int2* __restrict__ csr,
                                             const unsigned short* __restrict__ xin,
                                             unsigned short* __restrict__ xout) {
  const int lane = threadIdx.x & 63;
  const int wid = (blockIdx.x * blockDim.x + threadIdx.x) >> 6;
  const int nw = (gridDim.x * blockDim.x) >> 6;
  for (int n = wid; n < NN; n += nw)
    agg_row(n, lane, rowstart, deg, csr, xin, xout);
}

__global__ __launch_bounds__(256) void k_agg_list(const int* __restrict__ rowstart,
                                                  const int* __restrict__ deg,
                                                  const int2* __restrict__ csr,
                                                  const unsigned short* __restrict__ xin,
                                                  unsigned short* __restrict__ xout,
                                                  const int* __restrict__ list,
                                                  const int* __restrict__ lcnt) {
  const int lane = threadIdx.x & 63;
  const int wid = (blockIdx.x * blockDim.x + threadIdx.x) >> 6;
  const int nw = (gridDim.x * blockDim.x) >> 6;
  const int cl = *lcnt;
  for (int i = wid; i < cl; i += nw)
    agg_row(list[i], lane, rowstart, deg, csr, xin, xout);
}

// ---- gather + l2-normalize selected bf16 rows -> bf16 A-matrix slice ----
__global__ __launch_bounds__(256) void k_gnorm(const int* __restrict__ sl,
                                               const int* __restrict__ rl,
                                               const unsigned short* __restrict__ xin,
                                               unsigned short* __restrict__ Abf,
                                               int colbase) {
  const int lane = threadIdx.x & 63;
  const int row = blockIdx.x * 4 + (threadIdx.x >> 6);
  if (row >= MROWS) return;
  const int node = (row < SEL) ? sl[row] : rl[row - SEL];
  const unsigned v = ((const unsigned*)(xin + (size_t)node * DD))[lane];
  const float x0 = bflo(v), x1 = bfhi(v);
  float ss = fmaf(x0, x0, x1 * x1);
  #pragma unroll
  for (int m = 32; m >= 1; m >>= 1) ss += __shfl_xor(ss, m);
  const float sc = 1.0f / fmaxf(sqrtf(ss), 1e-12f);
  const unsigned short b0 = f2bf(x0 * sc), b1 = f2bf(x1 * sc);
  const unsigned pack = ((unsigned)b1 << 16) | (unsigned)b0;
  *(unsigned*)(Abf + (size_t)row * MD + colbase + lane * 2) = pack;
}

// ---- f32 -> bf16 bulk convert (W and emb) ----
__global__ void k_conv(const float* __restrict__ in, unsigned short* __restrict__ out,
                       int n4) {
  int i = blockIdx.x * blockDim.x + threadIdx.x;
  if (i >= n4) return;
  float4 v = ((const float4*)in)[i];
  ushort4 o;
  o.x = f2bf(v.x); o.y = f2bf(v.y); o.z = f2bf(v.z); o.w = f2bf(v.w);
  ((ushort4*)out)[i] = o;
}

// ---- MFMA GEMM: out[i][j] = sum_k A[i][k]*W[j][k] + bias[j] ----
__global__ __launch_bounds__(256) void k_gemm(const unsigned short* __restrict__ A,
                                              const unsigned short* __restrict__ B,
                                              const float* __restrict__ bias,
                                              float* __restrict__ out) {
  __shared__ unsigned short As[128][40];  // +8 pad breaks bank conflicts
  __shared__ unsigned short Bs[128][40];
  const int t = threadIdx.x;
  const int mt = blockIdx.x >> 2, nt = blockIdx.x & 3;
  const int i0 = mt * 128, j0 = nt * 128;
  const int lane = t & 63, wid = t >> 6;
  const int wr = wid >> 1, wc = wid & 1;    // 2x2 waves, 64x64 each
  const int fr = lane & 15, kg = lane >> 4; // fragment row/col, k-group
  f32x4 acc[4][4] = {};
  for (int k0 = 0; k0 < MD; k0 += 32) {
    #pragma unroll
    for (int rep = 0; rep < 2; ++rep) {
      int id = t + rep * 256;
      int row = id >> 2, seg = id & 3;  // 128 rows x 4 segs of 8 bf16
      float4 va = *(const float4*)(A + (size_t)(i0 + row) * MD + k0 + seg * 8);
      *(float4*)(&As[row][seg * 8]) = va;
      float4 vb = *(const float4*)(B + (size_t)(j0 + row) * MD + k0 + seg * 8);
      *(float4*)(&Bs[row][seg * 8]) = vb;
    }
    __syncthreads();
    bf16x8 af[4], bfr[4];
    #pragma unroll
    for (int m = 0; m < 4; ++m)
      af[m] = *(const bf16x8*)(&As[wr * 64 + m * 16 + fr][kg * 8]);
    #pragma unroll
    for (int n = 0; n < 4; ++n)
      bfr[n] = *(const bf16x8*)(&Bs[wc * 64 + n * 16 + fr][kg * 8]);
    #pragma unroll
    for (int m = 0; m < 4; ++m)
      #pragma unroll
      for (int n = 0; n < 4; ++n)
        acc[m][n] = __builtin_amdgcn_mfma_f32_16x16x32_bf16(af[m], bfr[n], acc[m][n], 0, 0, 0);
    __syncthreads();
  }
  #pragma unroll
  for (int n = 0; n < 4; ++n) {
    int col = j0 + wc * 64 + n * 16 + fr;
    float bv = bias[col];
    #pragma unroll
    for (int m = 0; m < 4; ++m) {
      int r0 = i0 + wr * 64 + m * 16 + kg * 4;
      #pragma unroll
      for (int r = 0; r < 4; ++r)
        out[(size_t)(r0 + r) * MD + col] = acc[m][n][r] + bv;
    }
  }
}

extern "C" void kernel_launch(void* const* d_in, const int* in_sizes, int n_in,
                              void* d_out, int out_size, void* d_ws, size_t ws_size,
                              hipStream_t stream) {
  const float* emb = (const float*)d_in[0];
  const int* ei = (const int*)d_in[1];
  const int* esrc = ei;                     // edge_index[0]
  const int* edst = ei + NE;                // edge_index[1]
  const int* send = (const int*)d_in[2];
  const int* recv = (const int*)d_in[3];
  const float* W = (const float*)d_in[4];
  const float* bias = (const float*)d_in[5];
  float* out = (float*)d_out;

  char* ws = (char*)d_ws;
  size_t off = 0;
  auto take = [&](size_t b) {
    char* p = ws + off;
    off = (off + b + 1023) & ~(size_t)1023;
    return p;
  };
  int* degI = (int*)take((size_t)NN * 4);
  float* dinv = (float*)take((size_t)NN * 4);
  int* rowstart = (int*)take((size_t)NN * 4);
  int* cursor = (int*)take((size_t)NN * 4);
  int* mark = (int*)take((size_t)NN * 4);
  int* list = (int*)take((size_t)MROWS * 4);
  int* lcnt = (int*)take(4);
  int* part = (int*)take(256 * 4);
  int2* csr = (int2*)take((size_t)NE * 8);
  unsigned short* x0 = (unsigned short*)take((size_t)NN * DD * 2);
  unsigned short* x1 = (unsigned short*)take((size_t)NN * DD * 2);
  unsigned short* x2 = (unsigned short*)take((size_t)NN * DD * 2);
  unsigned short* Abf = (unsigned short*)take((size_t)MROWS * MD * 2);
  unsigned short* Wbf = (unsigned short*)take((size_t)MD * MD * 2);
  (void)ws_size; (void)in_sizes; (void)n_in; (void)out_size;

  hipMemsetAsync(degI, 0, (size_t)NN * 4, stream);
  hipMemsetAsync(cursor, 0, (size_t)NN * 4, stream);
  hipMemsetAsync(mark, 0, (size_t)NN * 4, stream);
  hipMemsetAsync(lcnt, 0, 4, stream);

  k_deg<<<(NE + 255) / 256, 256, 0, stream>>>(edst, degI);
  k_dinv<<<(NN + 255) / 256, 256, 0, stream>>>(degI, dinv);
  const int NB = (NN + 1023) / 1024;
  k_scan1<<<NB, 1024, 0, stream>>>(degI, rowstart, part);
  k_scan2<<<1, 256, 0, stream>>>(part, NB);
  k_scan3<<<(NN + 255) / 256, 256, 0, stream>>>(rowstart, part);
  k_fill<<<(NE + 255) / 256, 256, 0, stream>>>(esrc, edst, dinv, rowstart, cursor, csr);
  k_mark<<<(2 * SEL + 255) / 256, 256, 0, stream>>>(send, recv, mark);
  k_compact<<<(NN + 255) / 256, 256, 0, stream>>>(mark, list, lcnt);
  k_conv<<<(MD * MD / 4 + 255) / 256, 256, 0, stream>>>(W, Wbf, MD * MD / 4);
  k_conv<<<(NN * DD / 4 + 255) / 256, 256, 0, stream>>>(emb, x0, NN * DD / 4);

  // z1 slice from bf16 emb; 2 full layers; masked final layer (reuses x0)
  k_gnorm<<<MROWS / 4, 256, 0, stream>>>(send, recv, x0, Abf, 0);
  k_agg<<<2048, 256, 0, stream>>>(rowstart, degI, csr, x0, x1);
  k_gnorm<<<MROWS / 4, 256, 0, stream>>>(send, recv, x1, Abf, 128);
  k_agg<<<2048, 256, 0, stream>>>(rowstart, degI, csr, x1, x2);
  k_gnorm<<<MROWS / 4, 256, 0, stream>>>(send, recv, x2, Abf, 256);
  k_agg_list<<<1024, 256, 0, stream>>>(rowstart, degI, csr, x2, x0, list, lcnt);
  k_gnorm<<<MROWS / 4, 256, 0, stream>>>(send, recv, x0, Abf, 384);

  k_gemm<<<(MROWS / 128) * (MD / 128), 256, 0, stream>>>(Abf, Wbf, bias, out);
}